// Round 1
// 1231.303 us; speedup vs baseline: 1.8933x; 1.8933x over previous
//
#include <hip/hip_runtime.h>
#include <math.h>

#define NN 4096
#define FF 256
#define RR 8
#define BQ 16384

typedef _Float16 half_t;
typedef half_t v8h __attribute__((ext_vector_type(8)));
typedef float  v4f __attribute__((ext_vector_type(4)));

// G values are scaled by 1/64 before the fp16 split (layer-2 G reaches ~1.2e5,
// fp16 max = 65504); gemm_ag epilogue multiplies the 64 back in.
#define G_SCALE     0.015625f
#define G_SCALE_INV 64.0f

// ---------------------------------------------------------------------------
// Kernel 1: G[r] = H @ W[r]^T, written TRANSPOSED and SPLIT to fp16 hi/lo:
//   Ght/Glt layout [r][f][m] (k-contiguous for the gemm_ag B-fragment reads).
// Main loop identical to the proven fp32 64x64 tile; epilogue transposes the
// 64x64 acc tile through LDS and emits coalesced half8 stores.
// ---------------------------------------------------------------------------
__global__ __launch_bounds__(256) void gemm_g(const float* __restrict__ H,
                                              const float* __restrict__ W,
                                              half_t* __restrict__ Ght,
                                              half_t* __restrict__ Glt) {
    __shared__ float smem[2 * 32 * 68];           // 17408 B, reused by epilogue
    float (*Hs)[68] = (float(*)[68])smem;         // [k][m-row]
    float (*Ws)[68] = (float(*)[68])(smem + 2176);// [k][f-row]

    const int tid = threadIdx.x;
    const int r   = blockIdx.z;
    const int o0  = blockIdx.x * 64;   // f
    const int m0  = blockIdx.y * 64;   // m
    const int tx  = tid & 15;
    const int ty  = tid >> 4;

    const float* __restrict__ Wr = W + (size_t)r * FF * FF;

    const int lr = tid >> 2;        // row 0..63
    const int lc = (tid & 3) * 8;   // k offset 0,8,16,24

    float acc[4][4];
#pragma unroll
    for (int i = 0; i < 4; ++i)
#pragma unroll
        for (int j = 0; j < 4; ++j) acc[i][j] = 0.0f;

    for (int fb = 0; fb < FF; fb += 32) {
        float4 h0 = *(const float4*)&H[(size_t)(m0 + lr) * FF + fb + lc];
        float4 h1 = *(const float4*)&H[(size_t)(m0 + lr) * FF + fb + lc + 4];
        float4 w0 = *(const float4*)&Wr[(size_t)(o0 + lr) * FF + fb + lc];
        float4 w1 = *(const float4*)&Wr[(size_t)(o0 + lr) * FF + fb + lc + 4];

        __syncthreads();
        Hs[lc + 0][lr] = h0.x;  Hs[lc + 1][lr] = h0.y;
        Hs[lc + 2][lr] = h0.z;  Hs[lc + 3][lr] = h0.w;
        Hs[lc + 4][lr] = h1.x;  Hs[lc + 5][lr] = h1.y;
        Hs[lc + 6][lr] = h1.z;  Hs[lc + 7][lr] = h1.w;
        Ws[lc + 0][lr] = w0.x;  Ws[lc + 1][lr] = w0.y;
        Ws[lc + 2][lr] = w0.z;  Ws[lc + 3][lr] = w0.w;
        Ws[lc + 4][lr] = w1.x;  Ws[lc + 5][lr] = w1.y;
        Ws[lc + 6][lr] = w1.z;  Ws[lc + 7][lr] = w1.w;
        __syncthreads();

#pragma unroll
        for (int k = 0; k < 32; ++k) {
            float4 hv = *(const float4*)&Hs[k][ty * 4];
            float4 wv = *(const float4*)&Ws[k][tx * 4];
            float a[4] = {hv.x, hv.y, hv.z, hv.w};
            float b[4] = {wv.x, wv.y, wv.z, wv.w};
#pragma unroll
            for (int i = 0; i < 4; ++i)
#pragma unroll
                for (int j = 0; j < 4; ++j) acc[i][j] += a[i] * b[j];
        }
    }

    // ---- epilogue: transpose tile through LDS, split to fp16 hi/lo ----
    __syncthreads();                       // main-loop reads of Hs/Ws done
    float (*T)[65] = (float(*)[65])smem;   // [m_local][f_local], 4160 floats
#pragma unroll
    for (int i = 0; i < 4; ++i)
#pragma unroll
        for (int j = 0; j < 4; ++j)
            T[ty * 4 + i][tx * 4 + j] = acc[i][j] * G_SCALE;
    __syncthreads();

    const int fr = tid >> 2;          // f_local 0..63
    const int mc = (tid & 3) << 4;    // m_local chunk 0,16,32,48
    v8h h0, h1, l0, l1;
#pragma unroll
    for (int q = 0; q < 8; ++q) {
        float v = T[mc + q][fr];
        half_t hh = (half_t)v;
        h0[q] = hh;
        l0[q] = (half_t)(v - (float)hh);
    }
#pragma unroll
    for (int q = 0; q < 8; ++q) {
        float v = T[mc + 8 + q][fr];
        half_t hh = (half_t)v;
        h1[q] = hh;
        l1[q] = (half_t)(v - (float)hh);
    }
    const size_t off = ((size_t)r * FF + o0 + fr) * NN + m0 + mc;
    *(v8h*)(Ght + off)     = h0;
    *(v8h*)(Ght + off + 8) = h1;
    *(v8h*)(Glt + off)     = l0;
    *(v8h*)(Glt + off + 8) = l1;
}

// ---------------------------------------------------------------------------
// Kernel 2: P[r] = c[r] * (A[r] @ G[r])  via fp16-split MFMA emulation.
//   A (fp32, HBM) is split to 2xfp16 on the fly during LDS staging.
//   B (Ght/Glt, [r][f][m]) is already split + k-contiguous.
//   acc += Ah*Bh + Ah*Bl + Al*Bh   (ll term ~2^-22, dropped)
// 128x128 tile, BK=32, 4 waves (2x2), per-wave 4x4 frags of 16x16x32 f16.
// LDS rows padded to 40 halves (80B) -> 2-way bank aliasing only (free).
// ---------------------------------------------------------------------------
__global__ __launch_bounds__(256, 2) void gemm_ag(const float* __restrict__ A,
                                                  const half_t* __restrict__ Ght,
                                                  const half_t* __restrict__ Glt,
                                                  const float* __restrict__ c,
                                                  float* __restrict__ P) {
    __shared__ half_t Ah[128][40];
    __shared__ half_t Al[128][40];
    __shared__ half_t Bh[128][40];
    __shared__ half_t Bl[128][40];

    const int tid = threadIdx.x;
    const int r   = blockIdx.z;
    const int f0  = blockIdx.x * 128;
    const int m0  = blockIdx.y * 128;

    const float*  __restrict__ Ar  = A   + (size_t)r * NN * NN;
    const half_t* __restrict__ BhG = Ght + ((size_t)r * FF + f0) * NN;
    const half_t* __restrict__ BlG = Glt + ((size_t)r * FF + f0) * NN;

    // staging decomposition: thread covers 16 consecutive k of one row
    const int srow  = tid >> 1;        // 0..127
    const int skoff = (tid & 1) * 16;  // 0 or 16 (elements)

    // wave decomposition: 2x2 waves, each owns a 64x64 sub-tile
    const int wid  = tid >> 6;
    const int lane = tid & 63;
    const int wr   = wid >> 1;           // m
    const int wc   = wid & 1;            // f
    const int lrow = lane & 15;
    const int lk   = (lane >> 4) * 8;    // k offset within BK

    v4f acc[4][4];
#pragma unroll
    for (int m = 0; m < 4; ++m)
#pragma unroll
        for (int n = 0; n < 4; ++n) acc[m][n] = (v4f){0.f, 0.f, 0.f, 0.f};

    const float*  Arow  = Ar  + (size_t)(m0 + srow) * NN;
    const half_t* Bhrow = BhG + (size_t)srow * NN;
    const half_t* Blrow = BlG + (size_t)srow * NN;

    // prefetch K-tile 0 into registers
    float4 pa0 = *(const float4*)(Arow + skoff);
    float4 pa1 = *(const float4*)(Arow + skoff + 4);
    float4 pa2 = *(const float4*)(Arow + skoff + 8);
    float4 pa3 = *(const float4*)(Arow + skoff + 12);
    float4 pbh0 = *(const float4*)(Bhrow + skoff);
    float4 pbh1 = *(const float4*)(Bhrow + skoff + 8);
    float4 pbl0 = *(const float4*)(Blrow + skoff);
    float4 pbl1 = *(const float4*)(Blrow + skoff + 8);

    for (int kb = 0; kb < NN; kb += 32) {
        __syncthreads();
        // ---- stage: split A fp32 -> fp16 hi/lo, copy B (already fp16) ----
        {
            float av[16];
            *(float4*)(av + 0)  = pa0;
            *(float4*)(av + 4)  = pa1;
            *(float4*)(av + 8)  = pa2;
            *(float4*)(av + 12) = pa3;
            v8h h0, h1, l0, l1;
#pragma unroll
            for (int e = 0; e < 8; ++e) {
                half_t hh = (half_t)av[e];
                h0[e] = hh;
                l0[e] = (half_t)(av[e] - (float)hh);
            }
#pragma unroll
            for (int e = 0; e < 8; ++e) {
                half_t hh = (half_t)av[8 + e];
                h1[e] = hh;
                l1[e] = (half_t)(av[8 + e] - (float)hh);
            }
            *(v8h*)&Ah[srow][skoff]     = h0;
            *(v8h*)&Ah[srow][skoff + 8] = h1;
            *(v8h*)&Al[srow][skoff]     = l0;
            *(v8h*)&Al[srow][skoff + 8] = l1;
            *(float4*)&Bh[srow][skoff]     = pbh0;
            *(float4*)&Bh[srow][skoff + 8] = pbh1;
            *(float4*)&Bl[srow][skoff]     = pbl0;
            *(float4*)&Bl[srow][skoff + 8] = pbl1;
        }
        __syncthreads();

        // ---- prefetch next K-tile while computing this one ----
        if (kb + 32 < NN) {
            const int kn = kb + 32;
            pa0 = *(const float4*)(Arow + kn + skoff);
            pa1 = *(const float4*)(Arow + kn + skoff + 4);
            pa2 = *(const float4*)(Arow + kn + skoff + 8);
            pa3 = *(const float4*)(Arow + kn + skoff + 12);
            pbh0 = *(const float4*)(Bhrow + kn + skoff);
            pbh1 = *(const float4*)(Bhrow + kn + skoff + 8);
            pbl0 = *(const float4*)(Blrow + kn + skoff);
            pbl1 = *(const float4*)(Blrow + kn + skoff + 8);
        }

        // ---- compute: 16 ds_read_b128 + 48 MFMA per wave ----
        v8h bh[4], bl[4];
#pragma unroll
        for (int n = 0; n < 4; ++n) {
            const int bc = wc * 64 + n * 16 + lrow;
            bh[n] = *(const v8h*)&Bh[bc][lk];
            bl[n] = *(const v8h*)&Bl[bc][lk];
        }
#pragma unroll
        for (int m = 0; m < 4; ++m) {
            const int ar = wr * 64 + m * 16 + lrow;
            v8h ahf = *(const v8h*)&Ah[ar][lk];
            v8h alf = *(const v8h*)&Al[ar][lk];
#pragma unroll
            for (int n = 0; n < 4; ++n) {
                acc[m][n] = __builtin_amdgcn_mfma_f32_16x16x32_f16(alf, bh[n], acc[m][n], 0, 0, 0);
                acc[m][n] = __builtin_amdgcn_mfma_f32_16x16x32_f16(ahf, bl[n], acc[m][n], 0, 0, 0);
                acc[m][n] = __builtin_amdgcn_mfma_f32_16x16x32_f16(ahf, bh[n], acc[m][n], 0, 0, 0);
            }
        }
    }

    // ---- epilogue: scale by c[r,m] * 64 (undo G_SCALE), store P plane ----
    // C/D layout (m89-verified): col = lane&15, row = (lane>>4)*4 + j
    float* __restrict__ Pp = P + (size_t)r * NN * FF;
#pragma unroll
    for (int m = 0; m < 4; ++m) {
        const int gm0 = m0 + wr * 64 + m * 16 + ((lane >> 4) << 2);
        float cv[4];
#pragma unroll
        for (int j = 0; j < 4; ++j)
            cv[j] = c[r * NN + gm0 + j] * G_SCALE_INV;
#pragma unroll
        for (int n = 0; n < 4; ++n) {
            const int gf = f0 + wc * 64 + n * 16 + (lane & 15);
#pragma unroll
            for (int j = 0; j < 4; ++j)
                Pp[(size_t)(gm0 + j) * FF + gf] = acc[m][n][j] * cv[j];
        }
    }
}

// ---------------------------------------------------------------------------
// Kernel 3: Hout = sum_r P[r]
// ---------------------------------------------------------------------------
__global__ __launch_bounds__(256) void reduce_p(const float* __restrict__ P,
                                                float* __restrict__ Hout) {
    const size_t idx = ((size_t)blockIdx.x * 256 + threadIdx.x) * 4;
    float4 s = *(const float4*)&P[idx];
#pragma unroll
    for (int r = 1; r < RR; ++r) {
        float4 v = *(const float4*)&P[(size_t)r * NN * FF + idx];
        s.x += v.x; s.y += v.y; s.z += v.z; s.w += v.w;
    }
    *(float4*)&Hout[idx] = s;
}

// ---------------------------------------------------------------------------
// Kernel 4: score[b] = sigmoid( sum_f E1[b,f] * Mdiag[rel[b],f] * E2[b,f] )
// ---------------------------------------------------------------------------
__global__ __launch_bounds__(256) void score_k(const float* __restrict__ H2,
                                               const float* __restrict__ relm,
                                               const int* __restrict__ e1,
                                               const int* __restrict__ rel,
                                               const int* __restrict__ e2,
                                               float* __restrict__ out) {
    const int wave = threadIdx.x >> 6;
    const int lane = threadIdx.x & 63;
    const int b = blockIdx.x * 4 + wave;
    if (b >= BQ) return;

    const int rr = rel[b];
    const float4* __restrict__ x = (const float4*)(H2 + (size_t)e1[b] * FF);
    const float4* __restrict__ y = (const float4*)(H2 + (size_t)e2[b] * FF);
    const float* __restrict__ M = relm + (size_t)rr * FF * FF;

    float4 xv = x[lane];
    float4 yv = y[lane];
    const int f = lane * 4;
    float s = xv.x * yv.x * M[(size_t)(f + 0) * (FF + 1)]
            + xv.y * yv.y * M[(size_t)(f + 1) * (FF + 1)]
            + xv.z * yv.z * M[(size_t)(f + 2) * (FF + 1)]
            + xv.w * yv.w * M[(size_t)(f + 3) * (FF + 1)];

#pragma unroll
    for (int off = 32; off > 0; off >>= 1) s += __shfl_down(s, off, 64);

    if (lane == 0) out[b] = 1.0f / (1.0f + expf(-s));
}

// ---------------------------------------------------------------------------
extern "C" void kernel_launch(void* const* d_in, const int* in_sizes, int n_in,
                              void* d_out, int out_size, void* d_ws, size_t ws_size,
                              hipStream_t stream) {
    const float* A    = (const float*)d_in[0];   // [R,N,N]
    const float* feat = (const float*)d_in[1];   // [N,F]
    const float* c    = (const float*)d_in[2];   // [R,N,1]
    const float* W1   = (const float*)d_in[3];   // [R,F,F]
    const float* W2   = (const float*)d_in[4];   // [R,F,F]
    const float* relm = (const float*)d_in[5];   // [R,F,F]
    const int*   e1   = (const int*)d_in[6];     // [B]
    const int*   rel  = (const int*)d_in[7];     // [B]
    const int*   e2   = (const int*)d_in[8];     // [B]
    float* out = (float*)d_out;                  // [B]

    // workspace: Ght 16.8MB | Glt 16.8MB | P 32MB | H 4MB  => ~71.3MB
    const size_t GT = (size_t)RR * FF * NN;      // 8,388,608 halves
    half_t* Ght = (half_t*)d_ws;
    half_t* Glt = Ght + GT;
    float*  P   = (float*)(Glt + GT);
    float*  H   = P + (size_t)RR * NN * FF;      // reused for H1 and H2

    dim3 gg(FF / 64, NN / 64, RR);       // (4, 64, 8)  = 2048 blocks
    dim3 ga(FF / 128, NN / 128, RR);     // (2, 32, 8)  = 512 blocks
    const int gr = (NN * FF / 4) / 256;  // 1024 blocks

    // Layer 1
    gemm_g  <<<gg, 256, 0, stream>>>(feat, W1, Ght, Glt);
    gemm_ag <<<ga, 256, 0, stream>>>(A, Ght, Glt, c, P);
    reduce_p<<<gr, 256, 0, stream>>>(P, H);
    // Layer 2
    gemm_g  <<<gg, 256, 0, stream>>>(H, W2, Ght, Glt);
    gemm_ag <<<ga, 256, 0, stream>>>(A, Ght, Glt, c, P);
    reduce_p<<<gr, 256, 0, stream>>>(P, H);
    // Scoring
    score_k<<<BQ / 4, 256, 0, stream>>>(H, relm, e1, rel, e2, out);
}